// Round 6
// baseline (7486.375 us; speedup 1.0000x reference)
//
#include <hip/hip_runtime.h>
#include <math.h>

#define NN 3136      // H*W = 56*56
#define CC 96
#define BB 8
#define KNB 9
#define PARTS 7      // m-range split for knn (7 parts x 448 cols)
#define CAND 12      // candidates kept per part (rescored in fp32)
#define NCAND (PARTS * CAND)   // 84
#define LROW 200     // LDS row pitch in ushorts (hi[0:96) lo[96:192) pad to 200)
#define FLT_MAX_ 3.402823466e+38f

typedef short short8 __attribute__((ext_vector_type(8)));
typedef float floatx4 __attribute__((ext_vector_type(4)));

__device__ __forceinline__ unsigned bf16_rne(float x)
{
    unsigned u = __float_as_uint(x);
    return (u + 0x7fffu + ((u >> 16) & 1u)) >> 16;
}

// length-L sorted insertion, lexicographic (d, m) — matches stable top_k ties
template<int L>
__device__ __forceinline__ void insL(float (&dv)[L], int (&di)[L], float d, int m)
{
    if (d < dv[L - 1] || (d == dv[L - 1] && m < di[L - 1])) {
        dv[L - 1] = d; di[L - 1] = m;
        #pragma unroll
        for (int j = L - 1; j > 0; --j) {
            bool sw = (dv[j] < dv[j - 1]) ||
                      (dv[j] == dv[j - 1] && di[j] < di[j - 1]);
            if (sw) {
                float tv = dv[j]; dv[j] = dv[j - 1]; dv[j - 1] = tv;
                int   ti = di[j]; di[j] = di[j - 1]; di[j - 1] = ti;
            }
        }
    }
}

// ---------------------------------------------------------------------------
// 1x1 conv as batched GEMM (fp32 vector): out[b,o,n] = bias[o] + sum_k w*in
// ---------------------------------------------------------------------------
__global__ __launch_bounds__(256) void conv1_kernel(
    const float* __restrict__ in, const float* __restrict__ w,
    const float* __restrict__ bias, float* __restrict__ out, int K, int O)
{
    __shared__ float sW[16][64];   // [kk][o]
    __shared__ float sX[16][64];   // [kk][n]
    const int b  = blockIdx.z;
    const int n0 = blockIdx.x * 64;
    const int o0 = blockIdx.y * 64;
    const int tid = threadIdx.x;
    const int tx = tid & 15, ty = tid >> 4;
    const float* inb = in + (size_t)b * K * NN;

    float acc[4][4] = {{0.f}};

    for (int kb = 0; kb < K; kb += 16) {
        __syncthreads();
        {
            int o  = tid >> 2;
            int k4 = (tid & 3) << 2;
            float4 wv = make_float4(0.f, 0.f, 0.f, 0.f);
            if (o0 + o < O)
                wv = *(const float4*)&w[(size_t)(o0 + o) * K + kb + k4];
            sW[k4 + 0][o] = wv.x; sW[k4 + 1][o] = wv.y;
            sW[k4 + 2][o] = wv.z; sW[k4 + 3][o] = wv.w;
        }
        #pragma unroll
        for (int i = 0; i < 4; i++) {
            int e = tid + i * 256;
            int kk = e >> 6, n2 = e & 63;
            sX[kk][n2] = inb[(size_t)(kb + kk) * NN + n0 + n2];
        }
        __syncthreads();
        #pragma unroll
        for (int kk = 0; kk < 16; kk++) {
            const float4 av = *(const float4*)&sW[kk][ty << 2];
            const float4 xv = *(const float4*)&sX[kk][tx << 2];
            float a_[4] = {av.x, av.y, av.z, av.w};
            float x_[4] = {xv.x, xv.y, xv.z, xv.w};
            #pragma unroll
            for (int i = 0; i < 4; i++)
                #pragma unroll
                for (int j = 0; j < 4; j++)
                    acc[i][j] = fmaf(a_[i], x_[j], acc[i][j]);
        }
    }
    #pragma unroll
    for (int i = 0; i < 4; i++) {
        int o = o0 + (ty << 2) + i;
        if (o < O) {
            float bo = bias[o];
            float4 v = make_float4(acc[i][0] + bo, acc[i][1] + bo,
                                   acc[i][2] + bo, acc[i][3] + bo);
            *(float4*)&out[((size_t)b * O + o) * NN + n0 + (tx << 2)] = v;
        }
    }
}

// ---------------------------------------------------------------------------
// Instance norm over N per (b,c) row; act: 0 none, 1 gelu, 2 relu
// ---------------------------------------------------------------------------
__global__ __launch_bounds__(256) void inorm_kernel(
    const float* __restrict__ in, float* __restrict__ out,
    const float* __restrict__ res, int act)
{
    const int row = blockIdx.x;
    const float* x = in + (size_t)row * NN;
    const int tid = threadIdx.x;

    float v[13];
    float s = 0.f;
    #pragma unroll
    for (int i = 0; i < 13; i++) {
        int idx = tid + i * 256;
        v[i] = (idx < NN) ? x[idx] : 0.f;
        s += v[i];
    }
    __shared__ float red[4];
    #pragma unroll
    for (int off = 32; off > 0; off >>= 1) s += __shfl_down(s, off);
    if ((tid & 63) == 0) red[tid >> 6] = s;
    __syncthreads();
    const float mean = (red[0] + red[1] + red[2] + red[3]) * (1.f / (float)NN);

    float s2 = 0.f;
    #pragma unroll
    for (int i = 0; i < 13; i++) {
        int idx = tid + i * 256;
        if (idx < NN) { float d = v[i] - mean; s2 = fmaf(d, d, s2); }
    }
    #pragma unroll
    for (int off = 32; off > 0; off >>= 1) s2 += __shfl_down(s2, off);
    __syncthreads();
    if ((tid & 63) == 0) red[tid >> 6] = s2;
    __syncthreads();
    const float var = (red[0] + red[1] + red[2] + red[3]) * (1.f / (float)NN);
    const float rs = rsqrtf(var + 1e-5f);

    float* o = out + (size_t)row * NN;
    const float* rr = res ? (res + (size_t)row * NN) : nullptr;
    #pragma unroll
    for (int i = 0; i < 13; i++) {
        int idx = tid + i * 256;
        if (idx < NN) {
            float y = (v[i] - mean) * rs;
            if (act == 1)      y = 0.5f * y * (1.f + erff(y * 0.70710678118654752f));
            else if (act == 2) y = fmaxf(y, 0.f);
            if (rr) y += rr[idx];
            o[idx] = y;
        }
    }
}

// ---------------------------------------------------------------------------
// Column L2-normalize. Writes:
//   xnf[b][n][c]  fp32 transposed (exact-rescore input, same arithmetic as
//                 the R2-passing fp32 pipeline)
//   xnt[b][n][hi 0:96 | lo 96:192] split-bf16 (candidate-generation MFMA)
//   sqc[b][n] = sum_c t^2, sequential fma (exact-rescore term)
// ---------------------------------------------------------------------------
__global__ __launch_bounds__(256) void colnorm_kernel(
    const float* __restrict__ xf, float* __restrict__ xnf,
    unsigned short* __restrict__ xnt, float* __restrict__ sqc)
{
    const int g = blockIdx.x * 256 + threadIdx.x;   // over B*N
    const int b = g / NN;
    const int n = g - b * NN;
    const float* p = xf + (size_t)b * CC * NN + n;
    unsigned int* q = (unsigned int*)(xnt + (size_t)g * (2 * CC));
    float* f = xnf + (size_t)g * CC;

    float s = 0.f;
    for (int c = 0; c < CC; c++) { float t = p[(size_t)c * NN]; s = fmaf(t, t, s); }
    const float den = fmaxf(sqrtf(s), 1e-12f);

    float sq = 0.f;
    for (int c = 0; c < CC; c += 2) {
        float t0 = p[(size_t)c * NN] / den;
        float t1 = p[(size_t)(c + 1) * NN] / den;
        f[c] = t0; f[c + 1] = t1;
        sq = fmaf(t0, t0, sq);
        sq = fmaf(t1, t1, sq);
        unsigned h0 = bf16_rne(t0), h1 = bf16_rne(t1);
        float f0 = __uint_as_float(h0 << 16), f1 = __uint_as_float(h1 << 16);
        unsigned l0 = bf16_rne(t0 - f0), l1 = bf16_rne(t1 - f1);
        q[c >> 1]        = h0 | (h1 << 16);
        q[48 + (c >> 1)] = l0 | (l1 << 16);
    }
    sqc[g] = sq;
}

// plain strict-< top-9 (per-lane candidate lists; ties immaterial here)
__device__ __forceinline__ void ins9(float (&dv)[9], int (&di)[9], float d, int m)
{
    if (d < dv[8]) {
        dv[8] = d; di[8] = m;
        #pragma unroll
        for (int j = 8; j > 0; --j) {
            if (dv[j] < dv[j - 1]) {
                float tv = dv[j]; dv[j] = dv[j - 1]; dv[j - 1] = tv;
                int   ti = di[j]; di[j] = di[j - 1]; di[j - 1] = ti;
            }
        }
    }
}

// ---------------------------------------------------------------------------
// kNN stage 1 (split-bf16 MFMA, CANDIDATE GENERATION): approx distances
// d[m] = sq[m] - 2*(hh+hl+lh) + rp[r,m]; per-row top-CAND(12) per part.
// NOTE: every loop touching dv[]/di[] MUST be fully unrolled — a dynamic
// index demotes the lists to scratch (R5: 5.8 GB spill traffic, 4x slower).
// ---------------------------------------------------------------------------
__global__ __launch_bounds__(256, 3) void knn_kernel(
    const unsigned short* __restrict__ xnt, const float* __restrict__ sqc,
    const float* __restrict__ rp, int* __restrict__ ci)
{
    __shared__ unsigned short shR[64 * LROW];   // 25.6 KB
    __shared__ unsigned short shC[64 * LROW];   // 25.6 KB
    const int b    = blockIdx.x;                // b fastest -> rp tile L2/L3 reuse
    const int r0   = blockIdx.y * 64;
    const int part = blockIdx.z;
    const int tid  = threadIdx.x;
    const int w    = tid >> 6;
    const int lane = tid & 63;
    const int m16  = lane & 15;
    const int quad = lane >> 4;
    const unsigned short* xb = xnt + (size_t)b * NN * (2 * CC);

    #pragma unroll
    for (int i = 0; i < 6; i++) {
        int ch = tid + i * 256;                 // 1536 16B chunks
        int row = ch / 24, seg = ch - row * 24;
        *(uint4*)&shR[row * LROW + seg * 8] =
            *(const uint4*)&xb[(size_t)(r0 + row) * 192 + seg * 8];
    }
    __syncthreads();

    short8 ah[3], al[3];
    #pragma unroll
    for (int s = 0; s < 3; s++) {
        ah[s] = *(const short8*)&shR[(w * 16 + m16) * LROW + s * 32 + quad * 8];
        al[s] = *(const short8*)&shR[(w * 16 + m16) * LROW + 96 + s * 32 + quad * 8];
    }

    float dv[4][9]; int di[4][9];
    #pragma unroll
    for (int r = 0; r < 4; r++)
        #pragma unroll
        for (int j = 0; j < 9; j++) { dv[r][j] = FLT_MAX_; di[r][j] = 0x7fffffff; }

    for (int chunk = 0; chunk < 7; chunk++) {
        const int m0 = part * 448 + chunk * 64;
        __syncthreads();
        #pragma unroll
        for (int i = 0; i < 6; i++) {
            int ch = tid + i * 256;
            int row = ch / 24, seg = ch - row * 24;
            *(uint4*)&shC[row * LROW + seg * 8] =
                *(const uint4*)&xb[(size_t)(m0 + row) * 192 + seg * 8];
        }
        __syncthreads();

        #pragma unroll
        for (int t = 0; t < 4; t++) {           // 4 col-tiles of 16
            floatx4 acc0 = {0.f, 0.f, 0.f, 0.f};
            floatx4 acc1 = {0.f, 0.f, 0.f, 0.f};
            floatx4 acc2 = {0.f, 0.f, 0.f, 0.f};
            #pragma unroll
            for (int s = 0; s < 3; s++) {
                const int base = (t * 16 + m16) * LROW + s * 32 + quad * 8;
                short8 bh = *(const short8*)&shC[base];
                short8 bl = *(const short8*)&shC[base + 96];
                acc0 = __builtin_amdgcn_mfma_f32_16x16x32_bf16(ah[s], bh, acc0, 0, 0, 0);
                acc1 = __builtin_amdgcn_mfma_f32_16x16x32_bf16(ah[s], bl, acc1, 0, 0, 0);
                acc2 = __builtin_amdgcn_mfma_f32_16x16x32_bf16(al[s], bh, acc2, 0, 0, 0);
            }
            const int m = m0 + t * 16 + m16;
            const float sq = sqc[(size_t)b * NN + m];
            #pragma unroll
            for (int reg = 0; reg < 4; reg++) {
                const int r = r0 + w * 16 + quad * 4 + reg;
                const float dot = acc0[reg] + acc1[reg] + acc2[reg];
                const float d = fmaf(-2.f, dot, sq + rp[(size_t)r * NN + m]);
                ins9(dv[reg], di[reg], d, m);
            }
        }
    }

    // merge 16 lane-lists/row -> part top-12: 256x9 -> 64x12 -> 16x12
    // reg loop MUST be unrolled: dv[reg]/di[reg] dynamic index => scratch spill
    float* mv  = (float*)shR;            // 2304 floats
    int*   mi  = (int*)shC;
    float* mv2 = mv + 2304;              // 768 floats
    int*   mi2 = mi + 2304;
    #pragma unroll
    for (int reg = 0; reg < 4; reg++) {
        __syncthreads();
        const int rr = w * 4 + quad;            // 0..15 pass-row
        #pragma unroll
        for (int j = 0; j < 9; j++) {
            mv[(rr * 16 + m16) * 9 + j] = dv[reg][j];
            mi[(rr * 16 + m16) * 9 + j] = di[reg][j];
        }
        __syncthreads();
        if (tid < 64) {
            const int rr2 = tid >> 2, qq = tid & 3;
            float bv[CAND]; int bi[CAND];
            #pragma unroll
            for (int j = 0; j < CAND; j++) { bv[j] = FLT_MAX_; bi[j] = 0x7fffffff; }
            for (int l = qq * 4; l < qq * 4 + 4; l++) {
                const int base = (rr2 * 16 + l) * 9;
                #pragma unroll
                for (int j = 0; j < 9; j++)
                    insL<CAND>(bv, bi, mv[base + j], mi[base + j]);
            }
            #pragma unroll
            for (int j = 0; j < CAND; j++) {
                mv2[tid * CAND + j] = bv[j]; mi2[tid * CAND + j] = bi[j];
            }
        }
        __syncthreads();
        if (tid < 16) {
            float bv[CAND]; int bi[CAND];
            #pragma unroll
            for (int j = 0; j < CAND; j++) { bv[j] = FLT_MAX_; bi[j] = 0x7fffffff; }
            for (int t2 = tid * 4; t2 < tid * 4 + 4; t2++) {
                #pragma unroll
                for (int j = 0; j < CAND; j++)
                    insL<CAND>(bv, bi, mv2[t2 * CAND + j], mi2[t2 * CAND + j]);
            }
            const int r = r0 + (tid >> 2) * 16 + (tid & 3) * 4 + reg;
            const size_t o = ((size_t)(b * NN + r) * PARTS + part) * CAND;
            #pragma unroll
            for (int j = 0; j < CAND; j++) ci[o + j] = bi[j];
        }
    }
}

// ---------------------------------------------------------------------------
// kNN stage 2 (EXACT RESCORE): per row, rescore all 84 candidates with the
// fp32 sequential-fma dot (bit-identical to the R2-passing pipeline), pick
// lexicographic (d,m) top-9. One block per row; candidates staged in LDS.
// ---------------------------------------------------------------------------
__global__ __launch_bounds__(128) void rescore_kernel(
    const float* __restrict__ xnf, const float* __restrict__ sqc,
    const float* __restrict__ rp, const int* __restrict__ ci,
    int* __restrict__ nn_idx)
{
    __shared__ float rv[CC];
    __shared__ float cand[NCAND * 97];      // 84*97*4B = 32.6 KB
    __shared__ int   cm[NCAND];
    __shared__ float cd[NCAND];
    const int g = blockIdx.x;               // b*NN + n
    const int b = g / NN;
    const int r = g - b * NN;
    const int tid = threadIdx.x;
    const float* xb = xnf + (size_t)b * NN * CC;

    if (tid < CC) rv[tid] = xb[(size_t)r * CC + tid];
    if (tid < NCAND) cm[tid] = ci[(size_t)g * NCAND + tid];
    __syncthreads();

    // stage candidate rows (coalesced float4 global reads, scalar LDS writes)
    for (int e = tid; e < NCAND * 24; e += 128) {
        int cr = e / 24, seg = e - cr * 24;
        float4 v = *(const float4*)&xb[(size_t)cm[cr] * CC + seg * 4];
        float* dst = &cand[cr * 97 + seg * 4];
        dst[0] = v.x; dst[1] = v.y; dst[2] = v.z; dst[3] = v.w;
    }
    __syncthreads();

    if (tid < NCAND) {
        const int m = cm[tid];
        float dot = 0.f;
        #pragma unroll 8
        for (int c = 0; c < CC; c++)
            dot = fmaf(rv[c], cand[tid * 97 + c], dot);
        cd[tid] = fmaf(-2.f, dot, sqc[(size_t)b * NN + m] + rp[(size_t)r * NN + m]);
    }
    __syncthreads();

    if (tid == 0) {
        float bv[9]; int bi[9];
        #pragma unroll
        for (int j = 0; j < 9; j++) { bv[j] = FLT_MAX_; bi[j] = 0x7fffffff; }
        for (int t = 0; t < NCAND; t++) insL<9>(bv, bi, cd[t], cm[t]);
        #pragma unroll
        for (int j = 0; j < 9; j++) nn_idx[(size_t)g * KNB + j] = bi[j];
    }
}

// ---------------------------------------------------------------------------
// Max-relative gather + channel interleave
// ---------------------------------------------------------------------------
__global__ __launch_bounds__(256) void gather_kernel(
    const float* __restrict__ xf, const int* __restrict__ nn_idx,
    float* __restrict__ y)
{
    const size_t g = (size_t)blockIdx.x * 256 + threadIdx.x;   // over B*C*N
    const int n  = (int)(g % NN);
    const int bc = (int)(g / NN);
    const int c  = bc % CC;
    const int b  = bc / CC;
    const float* row = xf + (size_t)(b * CC + c) * NN;
    const float xi = row[n];
    const int* id = nn_idx + ((size_t)b * NN + n) * KNB;
    float mx = -FLT_MAX_;
    #pragma unroll
    for (int k = 0; k < KNB; k++) mx = fmaxf(mx, row[id[k]] - xi);
    float* o = y + ((size_t)b * 2 * CC + 2 * c) * NN + n;
    o[0]  = xi;
    o[NN] = mx;
}

// ---------------------------------------------------------------------------
// Host-side orchestration
// ---------------------------------------------------------------------------
static void conv1(const float* in, const float* w, const float* b, float* out,
                  int K, int O, hipStream_t s)
{
    dim3 grid(NN / 64, (O + 63) / 64, BB);
    conv1_kernel<<<grid, 256, 0, s>>>(in, w, b, out, K, O);
}
static void inorm(const float* in, float* out, const float* res, int ch, int act,
                  hipStream_t s)
{
    inorm_kernel<<<BB * ch, 256, 0, s>>>(in, out, res, act);
}

struct GrapherP {
    const float *fc1w, *fc1b, *mrw, *mrb, *fc2w, *fc2b;
};

static void run_grapher(const float* in, const float* rp, const GrapherP& p,
                        float* outCur, float* bufA, float* bufB,
                        unsigned short* xnt, float* xnf, float* sqc, int* idx,
                        hipStream_t s)
{
    conv1(in, p.fc1w, p.fc1b, bufA, CC, CC, s);
    inorm(bufA, bufB, nullptr, CC, 0, s);                         // xf
    colnorm_kernel<<<(BB * NN) / 256, 256, 0, s>>>(bufB, xnf, xnt, sqc);
    int* ci = (int*)bufA;     // candidate scratch: B*N*84 ints (conv out dead)
    knn_kernel<<<dim3(BB, NN / 64, PARTS), 256, 0, s>>>(xnt, sqc, rp, ci);
    rescore_kernel<<<BB * NN, 128, 0, s>>>(xnf, sqc, rp, ci, idx);
    gather_kernel<<<(BB * CC * NN) / 256, 256, 0, s>>>(bufB, idx, bufA);  // 2C
    conv1(bufA, p.mrw, p.mrb, bufB, 2 * CC, 2 * CC, s);
    inorm(bufB, bufA, nullptr, 2 * CC, 1, s);                     // gelu
    conv1(bufA, p.fc2w, p.fc2b, bufB, 2 * CC, CC, s);
    inorm(bufB, outCur, in, CC, 0, s);                            // + shortcut
}

static void run_ffn(const float* in, const float* w1, const float* b1,
                    const float* w2, const float* b2,
                    float* outCur, float* bufA, float* bufB, hipStream_t s)
{
    conv1(in, w1, b1, bufA, CC, 4 * CC, s);
    inorm(bufA, bufB, nullptr, 4 * CC, 1, s);                     // gelu
    conv1(bufB, w2, b2, bufA, 4 * CC, CC, s);
    inorm(bufA, outCur, in, CC, 0, s);                            // + shortcut
}

extern "C" void kernel_launch(void* const* d_in, const int* in_sizes, int n_in,
                              void* d_out, int out_size, void* d_ws, size_t ws_size,
                              hipStream_t stream)
{
    const float* x  = (const float*)d_in[0];
    const float* rp = (const float*)d_in[1];
    GrapherP g1 = {(const float*)d_in[2],  (const float*)d_in[3],
                   (const float*)d_in[4],  (const float*)d_in[5],
                   (const float*)d_in[6],  (const float*)d_in[7]};
    GrapherP g2 = {(const float*)d_in[8],  (const float*)d_in[9],
                   (const float*)d_in[10], (const float*)d_in[11],
                   (const float*)d_in[12], (const float*)d_in[13]};
    const float* f1w1 = (const float*)d_in[14]; const float* f1b1 = (const float*)d_in[15];
    const float* f1w2 = (const float*)d_in[16]; const float* f1b2 = (const float*)d_in[17];
    const float* f2w1 = (const float*)d_in[18]; const float* f2b1 = (const float*)d_in[19];
    const float* f2w2 = (const float*)d_in[20]; const float* f2b2 = (const float*)d_in[21];
    float* out = (float*)d_out;

    const size_t P  = (size_t)BB * CC * NN;     // 2,408,448 floats
    const size_t P4 = 4 * P;
    float* ws   = (float*)d_ws;
    float* bufA = ws;                 // P4 (conv out / ci / gather out: disjoint in time)
    float* bufB = bufA + P4;          // P4
    unsigned short* xnt = (unsigned short*)(bufB + P4);   // B*N*192 us == P floats
    float* cur0 = (float*)xnt + P;    // P
    float* cur1 = cur0 + P;           // P
    float* sqc  = cur1 + P;           // B*N
    int*   idx  = (int*)(sqc + (size_t)BB * NN);          // B*N*9 ints
    // xnf overlays the TAIL of bufA: gather writes only [0, 2P) of bufA,
    // ci occupies [0, ~0.9P) — the tail [3P, 4P) is free through the knn phase.
    float* xnf = bufA + 3 * P;        // B*N*96 floats = P

    run_grapher(x, rp, g1, cur0, bufA, bufB, xnt, xnf, sqc, idx, stream);
    run_ffn(cur0, f1w1, f1b1, f1w2, f1b2, cur1, bufA, bufB, stream);
    inorm(cur1, cur0, nullptr, CC, 2, stream);
    run_grapher(cur0, rp, g2, cur1, bufA, bufB, xnt, xnf, sqc, idx, stream);
    run_ffn(cur1, f2w1, f2b1, f2w2, f2b2, cur0, bufA, bufB, stream);
    inorm(cur0, out, x, CC, 0, stream);
}

// Round 7
// 5938.562 us; speedup vs baseline: 1.2606x; 1.2606x over previous
//
#include <hip/hip_runtime.h>
#include <math.h>

#define NN 3136      // H*W = 56*56
#define CC 96
#define BB 8
#define KNB 9
#define PARTS 7      // m-range split for knn (7 parts x 448 cols)
#define CAND 12      // candidates kept per part (rescored in fp32)
#define NCAND (PARTS * CAND)   // 84
#define LROW 200     // LDS row pitch in ushorts (hi[0:96) lo[96:192) pad to 200)
#define FLT_MAX_ 3.402823466e+38f

typedef short short8 __attribute__((ext_vector_type(8)));
typedef float floatx4 __attribute__((ext_vector_type(4)));

__device__ __forceinline__ unsigned bf16_rne(float x)
{
    unsigned u = __float_as_uint(x);
    return (u + 0x7fffu + ((u >> 16) & 1u)) >> 16;
}

// length-L sorted insertion, lexicographic (d, m) — matches stable top_k ties
template<int L>
__device__ __forceinline__ void insL(float (&dv)[L], int (&di)[L], float d, int m)
{
    if (d < dv[L - 1] || (d == dv[L - 1] && m < di[L - 1])) {
        dv[L - 1] = d; di[L - 1] = m;
        #pragma unroll
        for (int j = L - 1; j > 0; --j) {
            bool sw = (dv[j] < dv[j - 1]) ||
                      (dv[j] == dv[j - 1] && di[j] < di[j - 1]);
            if (sw) {
                float tv = dv[j]; dv[j] = dv[j - 1]; dv[j - 1] = tv;
                int   ti = di[j]; di[j] = di[j - 1]; di[j - 1] = ti;
            }
        }
    }
}

// plain strict-< top-9 (per-lane candidate lists; ties immaterial here)
__device__ __forceinline__ void ins9(float (&dv)[9], int (&di)[9], float d, int m)
{
    if (d < dv[8]) {
        dv[8] = d; di[8] = m;
        #pragma unroll
        for (int j = 8; j > 0; --j) {
            if (dv[j] < dv[j - 1]) {
                float tv = dv[j]; dv[j] = dv[j - 1]; dv[j - 1] = tv;
                int   ti = di[j]; di[j] = di[j - 1]; di[j - 1] = ti;
            }
        }
    }
}

// ---------------------------------------------------------------------------
// 1x1 conv as batched GEMM (fp32 vector): out[b,o,n] = bias[o] + sum_k w*in
// ---------------------------------------------------------------------------
__global__ __launch_bounds__(256) void conv1_kernel(
    const float* __restrict__ in, const float* __restrict__ w,
    const float* __restrict__ bias, float* __restrict__ out, int K, int O)
{
    __shared__ float sW[16][64];   // [kk][o]
    __shared__ float sX[16][64];   // [kk][n]
    const int b  = blockIdx.z;
    const int n0 = blockIdx.x * 64;
    const int o0 = blockIdx.y * 64;
    const int tid = threadIdx.x;
    const int tx = tid & 15, ty = tid >> 4;
    const float* inb = in + (size_t)b * K * NN;

    float acc[4][4] = {{0.f}};

    for (int kb = 0; kb < K; kb += 16) {
        __syncthreads();
        {
            int o  = tid >> 2;
            int k4 = (tid & 3) << 2;
            float4 wv = make_float4(0.f, 0.f, 0.f, 0.f);
            if (o0 + o < O)
                wv = *(const float4*)&w[(size_t)(o0 + o) * K + kb + k4];
            sW[k4 + 0][o] = wv.x; sW[k4 + 1][o] = wv.y;
            sW[k4 + 2][o] = wv.z; sW[k4 + 3][o] = wv.w;
        }
        #pragma unroll
        for (int i = 0; i < 4; i++) {
            int e = tid + i * 256;
            int kk = e >> 6, n2 = e & 63;
            sX[kk][n2] = inb[(size_t)(kb + kk) * NN + n0 + n2];
        }
        __syncthreads();
        #pragma unroll
        for (int kk = 0; kk < 16; kk++) {
            const float4 av = *(const float4*)&sW[kk][ty << 2];
            const float4 xv = *(const float4*)&sX[kk][tx << 2];
            float a_[4] = {av.x, av.y, av.z, av.w};
            float x_[4] = {xv.x, xv.y, xv.z, xv.w};
            #pragma unroll
            for (int i = 0; i < 4; i++)
                #pragma unroll
                for (int j = 0; j < 4; j++)
                    acc[i][j] = fmaf(a_[i], x_[j], acc[i][j]);
        }
    }
    #pragma unroll
    for (int i = 0; i < 4; i++) {
        int o = o0 + (ty << 2) + i;
        if (o < O) {
            float bo = bias[o];
            float4 v = make_float4(acc[i][0] + bo, acc[i][1] + bo,
                                   acc[i][2] + bo, acc[i][3] + bo);
            *(float4*)&out[((size_t)b * O + o) * NN + n0 + (tx << 2)] = v;
        }
    }
}

// ---------------------------------------------------------------------------
// Instance norm over N per (b,c) row; act: 0 none, 1 gelu, 2 relu
// ---------------------------------------------------------------------------
__global__ __launch_bounds__(256) void inorm_kernel(
    const float* __restrict__ in, float* __restrict__ out,
    const float* __restrict__ res, int act)
{
    const int row = blockIdx.x;
    const float* x = in + (size_t)row * NN;
    const int tid = threadIdx.x;

    float v[13];
    float s = 0.f;
    #pragma unroll
    for (int i = 0; i < 13; i++) {
        int idx = tid + i * 256;
        v[i] = (idx < NN) ? x[idx] : 0.f;
        s += v[i];
    }
    __shared__ float red[4];
    #pragma unroll
    for (int off = 32; off > 0; off >>= 1) s += __shfl_down(s, off);
    if ((tid & 63) == 0) red[tid >> 6] = s;
    __syncthreads();
    const float mean = (red[0] + red[1] + red[2] + red[3]) * (1.f / (float)NN);

    float s2 = 0.f;
    #pragma unroll
    for (int i = 0; i < 13; i++) {
        int idx = tid + i * 256;
        if (idx < NN) { float d = v[i] - mean; s2 = fmaf(d, d, s2); }
    }
    #pragma unroll
    for (int off = 32; off > 0; off >>= 1) s2 += __shfl_down(s2, off);
    __syncthreads();
    if ((tid & 63) == 0) red[tid >> 6] = s2;
    __syncthreads();
    const float var = (red[0] + red[1] + red[2] + red[3]) * (1.f / (float)NN);
    const float rs = rsqrtf(var + 1e-5f);

    float* o = out + (size_t)row * NN;
    const float* rr = res ? (res + (size_t)row * NN) : nullptr;
    #pragma unroll
    for (int i = 0; i < 13; i++) {
        int idx = tid + i * 256;
        if (idx < NN) {
            float y = (v[i] - mean) * rs;
            if (act == 1)      y = 0.5f * y * (1.f + erff(y * 0.70710678118654752f));
            else if (act == 2) y = fmaxf(y, 0.f);
            if (rr) y += rr[idx];
            o[idx] = y;
        }
    }
}

// ---------------------------------------------------------------------------
// Column L2-normalize. Writes:
//   xnf[b][n][c]  fp32 transposed (exact-rescore input, same arithmetic as
//                 the R2-passing fp32 pipeline)
//   xnt[b][n][hi 0:96 | lo 96:192] split-bf16 (candidate-generation MFMA)
//   sqc[b][n] = sum_c t^2, sequential fma (exact-rescore term)
// ---------------------------------------------------------------------------
__global__ __launch_bounds__(256) void colnorm_kernel(
    const float* __restrict__ xf, float* __restrict__ xnf,
    unsigned short* __restrict__ xnt, float* __restrict__ sqc)
{
    const int g = blockIdx.x * 256 + threadIdx.x;   // over B*N
    const int b = g / NN;
    const int n = g - b * NN;
    const float* p = xf + (size_t)b * CC * NN + n;
    unsigned int* q = (unsigned int*)(xnt + (size_t)g * (2 * CC));
    float* f = xnf + (size_t)g * CC;

    float s = 0.f;
    for (int c = 0; c < CC; c++) { float t = p[(size_t)c * NN]; s = fmaf(t, t, s); }
    const float den = fmaxf(sqrtf(s), 1e-12f);

    float sq = 0.f;
    for (int c = 0; c < CC; c += 2) {
        float t0 = p[(size_t)c * NN] / den;
        float t1 = p[(size_t)(c + 1) * NN] / den;
        f[c] = t0; f[c + 1] = t1;
        sq = fmaf(t0, t0, sq);
        sq = fmaf(t1, t1, sq);
        unsigned h0 = bf16_rne(t0), h1 = bf16_rne(t1);
        float f0 = __uint_as_float(h0 << 16), f1 = __uint_as_float(h1 << 16);
        unsigned l0 = bf16_rne(t0 - f0), l1 = bf16_rne(t1 - f1);
        q[c >> 1]        = h0 | (h1 << 16);
        q[48 + (c >> 1)] = l0 | (l1 << 16);
    }
    sqc[g] = sq;
}

// ---------------------------------------------------------------------------
// kNN stage 1 (split-bf16 MFMA, CANDIDATE GENERATION): approx distances
// d[m] = sq[m] - 2*(hh+hl+lh) + rp[r,m]; per-row top-CAND(12) per part.
// SPILL DISCIPLINE (R5/R6: 5.7 GB scratch traffic, 4x slower): NO
// arrays-of-arrays anywhere. All per-lane lists are explicitly named
// scalars arrays with only constant indices; merge phase reads them via
// ternary selects (v_cndmask), never dynamic indexing.
// __launch_bounds__(256,2): relax VGPR cap (LDS caps blocks/CU at 3 anyway).
// ---------------------------------------------------------------------------
__global__ __launch_bounds__(256, 2) void knn_kernel(
    const unsigned short* __restrict__ xnt, const float* __restrict__ sqc,
    const float* __restrict__ rp, int* __restrict__ ci)
{
    __shared__ unsigned short shR[64 * LROW];   // 25.6 KB
    __shared__ unsigned short shC[64 * LROW];   // 25.6 KB
    const int b    = blockIdx.x;                // b fastest -> rp tile L2/L3 reuse
    const int r0   = blockIdx.y * 64;
    const int part = blockIdx.z;
    const int tid  = threadIdx.x;
    const int w    = tid >> 6;
    const int lane = tid & 63;
    const int m16  = lane & 15;
    const int quad = lane >> 4;
    const unsigned short* xb = xnt + (size_t)b * NN * (2 * CC);

    #pragma unroll
    for (int i = 0; i < 6; i++) {
        int ch = tid + i * 256;                 // 1536 16B chunks
        int row = ch / 24, seg = ch - row * 24;
        *(uint4*)&shR[row * LROW + seg * 8] =
            *(const uint4*)&xb[(size_t)(r0 + row) * 192 + seg * 8];
    }
    __syncthreads();

    const int abase = (w * 16 + m16) * LROW + quad * 8;
    const short8 ah0 = *(const short8*)&shR[abase];
    const short8 ah1 = *(const short8*)&shR[abase + 32];
    const short8 ah2 = *(const short8*)&shR[abase + 64];
    const short8 al0 = *(const short8*)&shR[abase + 96];
    const short8 al1 = *(const short8*)&shR[abase + 128];
    const short8 al2 = *(const short8*)&shR[abase + 160];

    float dv0[9], dv1[9], dv2[9], dv3[9];
    int   di0[9], di1[9], di2[9], di3[9];
    #pragma unroll
    for (int j = 0; j < 9; j++) {
        dv0[j] = dv1[j] = dv2[j] = dv3[j] = FLT_MAX_;
        di0[j] = di1[j] = di2[j] = di3[j] = 0x7fffffff;
    }

    const int rbase = r0 + w * 16 + quad * 4;
    const float* rpr0 = rp + (size_t)(rbase + 0) * NN;
    const float* rpr1 = rp + (size_t)(rbase + 1) * NN;
    const float* rpr2 = rp + (size_t)(rbase + 2) * NN;
    const float* rpr3 = rp + (size_t)(rbase + 3) * NN;
    const float* sqb  = sqc + (size_t)b * NN;

    for (int chunk = 0; chunk < 7; chunk++) {
        const int m0 = part * 448 + chunk * 64;
        __syncthreads();
        #pragma unroll
        for (int i = 0; i < 6; i++) {
            int ch = tid + i * 256;
            int row = ch / 24, seg = ch - row * 24;
            *(uint4*)&shC[row * LROW + seg * 8] =
                *(const uint4*)&xb[(size_t)(m0 + row) * 192 + seg * 8];
        }
        __syncthreads();

        #pragma unroll
        for (int t = 0; t < 4; t++) {           // 4 col-tiles of 16
            floatx4 acc0 = {0.f, 0.f, 0.f, 0.f};
            floatx4 acc1 = {0.f, 0.f, 0.f, 0.f};
            floatx4 acc2 = {0.f, 0.f, 0.f, 0.f};
            const int cbase = (t * 16 + m16) * LROW + quad * 8;
            {
                const short8 bh = *(const short8*)&shC[cbase];
                const short8 bl = *(const short8*)&shC[cbase + 96];
                acc0 = __builtin_amdgcn_mfma_f32_16x16x32_bf16(ah0, bh, acc0, 0, 0, 0);
                acc1 = __builtin_amdgcn_mfma_f32_16x16x32_bf16(ah0, bl, acc1, 0, 0, 0);
                acc2 = __builtin_amdgcn_mfma_f32_16x16x32_bf16(al0, bh, acc2, 0, 0, 0);
            }
            {
                const short8 bh = *(const short8*)&shC[cbase + 32];
                const short8 bl = *(const short8*)&shC[cbase + 128];
                acc0 = __builtin_amdgcn_mfma_f32_16x16x32_bf16(ah1, bh, acc0, 0, 0, 0);
                acc1 = __builtin_amdgcn_mfma_f32_16x16x32_bf16(ah1, bl, acc1, 0, 0, 0);
                acc2 = __builtin_amdgcn_mfma_f32_16x16x32_bf16(al1, bh, acc2, 0, 0, 0);
            }
            {
                const short8 bh = *(const short8*)&shC[cbase + 64];
                const short8 bl = *(const short8*)&shC[cbase + 160];
                acc0 = __builtin_amdgcn_mfma_f32_16x16x32_bf16(ah2, bh, acc0, 0, 0, 0);
                acc1 = __builtin_amdgcn_mfma_f32_16x16x32_bf16(ah2, bl, acc1, 0, 0, 0);
                acc2 = __builtin_amdgcn_mfma_f32_16x16x32_bf16(al2, bh, acc2, 0, 0, 0);
            }
            const int m = m0 + t * 16 + m16;
            const float sqm = sqc ? sqb[m] : 0.f;
            ins9(dv0, di0, fmaf(-2.f, acc0[0] + acc1[0] + acc2[0], sqm + rpr0[m]), m);
            ins9(dv1, di1, fmaf(-2.f, acc0[1] + acc1[1] + acc2[1], sqm + rpr1[m]), m);
            ins9(dv2, di2, fmaf(-2.f, acc0[2] + acc1[2] + acc2[2], sqm + rpr2[m]), m);
            ins9(dv3, di3, fmaf(-2.f, acc0[3] + acc1[3] + acc2[3], sqm + rpr3[m]), m);
        }
    }

    // merge 16 lane-lists/row -> part top-12: 256x9 -> 64x12 -> 16x12
    // lists read via ternary select on reg (cndmask) — NO dynamic indexing
    float* mv  = (float*)shR;            // 2304 floats
    int*   mi  = (int*)shC;
    float* mv2 = mv + 2304;              // 768 floats
    int*   mi2 = mi + 2304;
    for (int reg = 0; reg < 4; reg++) {
        __syncthreads();
        const int rr = w * 4 + quad;            // 0..15 pass-row
        #pragma unroll
        for (int j = 0; j < 9; j++) {
            float v = (reg == 0) ? dv0[j] : (reg == 1) ? dv1[j]
                    : (reg == 2) ? dv2[j] : dv3[j];
            int   q = (reg == 0) ? di0[j] : (reg == 1) ? di1[j]
                    : (reg == 2) ? di2[j] : di3[j];
            mv[(rr * 16 + m16) * 9 + j] = v;
            mi[(rr * 16 + m16) * 9 + j] = q;
        }
        __syncthreads();
        if (tid < 64) {
            const int rr2 = tid >> 2, qq = tid & 3;
            float bv[CAND]; int bi[CAND];
            #pragma unroll
            for (int j = 0; j < CAND; j++) { bv[j] = FLT_MAX_; bi[j] = 0x7fffffff; }
            for (int l = qq * 4; l < qq * 4 + 4; l++) {
                const int base = (rr2 * 16 + l) * 9;
                #pragma unroll
                for (int j = 0; j < 9; j++)
                    insL<CAND>(bv, bi, mv[base + j], mi[base + j]);
            }
            #pragma unroll
            for (int j = 0; j < CAND; j++) {
                mv2[tid * CAND + j] = bv[j]; mi2[tid * CAND + j] = bi[j];
            }
        }
        __syncthreads();
        if (tid < 16) {
            float bv[CAND]; int bi[CAND];
            #pragma unroll
            for (int j = 0; j < CAND; j++) { bv[j] = FLT_MAX_; bi[j] = 0x7fffffff; }
            for (int t2 = tid * 4; t2 < tid * 4 + 4; t2++) {
                #pragma unroll
                for (int j = 0; j < CAND; j++)
                    insL<CAND>(bv, bi, mv2[t2 * CAND + j], mi2[t2 * CAND + j]);
            }
            const int r = r0 + (tid >> 2) * 16 + (tid & 3) * 4 + reg;
            const size_t o = ((size_t)(b * NN + r) * PARTS + part) * CAND;
            #pragma unroll
            for (int j = 0; j < CAND; j++) ci[o + j] = bi[j];
        }
    }
}

// ---------------------------------------------------------------------------
// kNN stage 2 (EXACT RESCORE): per row, rescore all 84 candidates with the
// fp32 sequential-fma dot (bit-identical to the R2-passing pipeline), pick
// lexicographic (d,m) top-9. One block per row; candidates staged in LDS.
// ---------------------------------------------------------------------------
__global__ __launch_bounds__(128) void rescore_kernel(
    const float* __restrict__ xnf, const float* __restrict__ sqc,
    const float* __restrict__ rp, const int* __restrict__ ci,
    int* __restrict__ nn_idx)
{
    __shared__ float rv[CC];
    __shared__ float cand[NCAND * 97];      // 84*97*4B = 32.6 KB
    __shared__ int   cm[NCAND];
    __shared__ float cd[NCAND];
    const int g = blockIdx.x;               // b*NN + n
    const int b = g / NN;
    const int r = g - b * NN;
    const int tid = threadIdx.x;
    const float* xb = xnf + (size_t)b * NN * CC;

    if (tid < CC) rv[tid] = xb[(size_t)r * CC + tid];
    if (tid < NCAND) cm[tid] = ci[(size_t)g * NCAND + tid];
    __syncthreads();

    // stage candidate rows (coalesced float4 global reads, scalar LDS writes)
    for (int e = tid; e < NCAND * 24; e += 128) {
        int cr = e / 24, seg = e - cr * 24;
        float4 v = *(const float4*)&xb[(size_t)cm[cr] * CC + seg * 4];
        float* dst = &cand[cr * 97 + seg * 4];
        dst[0] = v.x; dst[1] = v.y; dst[2] = v.z; dst[3] = v.w;
    }
    __syncthreads();

    if (tid < NCAND) {
        const int m = cm[tid];
        float dot = 0.f;
        #pragma unroll 8
        for (int c = 0; c < CC; c++)
            dot = fmaf(rv[c], cand[tid * 97 + c], dot);
        cd[tid] = fmaf(-2.f, dot, sqc[(size_t)b * NN + m] + rp[(size_t)r * NN + m]);
    }
    __syncthreads();

    if (tid == 0) {
        float bv[9]; int bi[9];
        #pragma unroll
        for (int j = 0; j < 9; j++) { bv[j] = FLT_MAX_; bi[j] = 0x7fffffff; }
        for (int t = 0; t < NCAND; t++) insL<9>(bv, bi, cd[t], cm[t]);
        #pragma unroll
        for (int j = 0; j < 9; j++) nn_idx[(size_t)g * KNB + j] = bi[j];
    }
}

// ---------------------------------------------------------------------------
// Max-relative gather + channel interleave
// ---------------------------------------------------------------------------
__global__ __launch_bounds__(256) void gather_kernel(
    const float* __restrict__ xf, const int* __restrict__ nn_idx,
    float* __restrict__ y)
{
    const size_t g = (size_t)blockIdx.x * 256 + threadIdx.x;   // over B*C*N
    const int n  = (int)(g % NN);
    const int bc = (int)(g / NN);
    const int c  = bc % CC;
    const int b  = bc / CC;
    const float* row = xf + (size_t)(b * CC + c) * NN;
    const float xi = row[n];
    const int* id = nn_idx + ((size_t)b * NN + n) * KNB;
    float mx = -FLT_MAX_;
    #pragma unroll
    for (int k = 0; k < KNB; k++) mx = fmaxf(mx, row[id[k]] - xi);
    float* o = y + ((size_t)b * 2 * CC + 2 * c) * NN + n;
    o[0]  = xi;
    o[NN] = mx;
}

// ---------------------------------------------------------------------------
// Host-side orchestration
// ---------------------------------------------------------------------------
static void conv1(const float* in, const float* w, const float* b, float* out,
                  int K, int O, hipStream_t s)
{
    dim3 grid(NN / 64, (O + 63) / 64, BB);
    conv1_kernel<<<grid, 256, 0, s>>>(in, w, b, out, K, O);
}
static void inorm(const float* in, float* out, const float* res, int ch, int act,
                  hipStream_t s)
{
    inorm_kernel<<<BB * ch, 256, 0, s>>>(in, out, res, act);
}

struct GrapherP {
    const float *fc1w, *fc1b, *mrw, *mrb, *fc2w, *fc2b;
};

static void run_grapher(const float* in, const float* rp, const GrapherP& p,
                        float* outCur, float* bufA, float* bufB,
                        unsigned short* xnt, float* xnf, float* sqc, int* idx,
                        hipStream_t s)
{
    conv1(in, p.fc1w, p.fc1b, bufA, CC, CC, s);
    inorm(bufA, bufB, nullptr, CC, 0, s);                         // xf
    colnorm_kernel<<<(BB * NN) / 256, 256, 0, s>>>(bufB, xnf, xnt, sqc);
    int* ci = (int*)bufA;     // candidate scratch: B*N*84 ints (conv out dead)
    knn_kernel<<<dim3(BB, NN / 64, PARTS), 256, 0, s>>>(xnt, sqc, rp, ci);
    rescore_kernel<<<BB * NN, 128, 0, s>>>(xnf, sqc, rp, ci, idx);
    gather_kernel<<<(BB * CC * NN) / 256, 256, 0, s>>>(bufB, idx, bufA);  // 2C
    conv1(bufA, p.mrw, p.mrb, bufB, 2 * CC, 2 * CC, s);
    inorm(bufB, bufA, nullptr, 2 * CC, 1, s);                     // gelu
    conv1(bufA, p.fc2w, p.fc2b, bufB, 2 * CC, CC, s);
    inorm(bufB, outCur, in, CC, 0, s);                            // + shortcut
}

static void run_ffn(const float* in, const float* w1, const float* b1,
                    const float* w2, const float* b2,
                    float* outCur, float* bufA, float* bufB, hipStream_t s)
{
    conv1(in, w1, b1, bufA, CC, 4 * CC, s);
    inorm(bufA, bufB, nullptr, 4 * CC, 1, s);                     // gelu
    conv1(bufB, w2, b2, bufA, 4 * CC, CC, s);
    inorm(bufA, outCur, in, CC, 0, s);                            // + shortcut
}

extern "C" void kernel_launch(void* const* d_in, const int* in_sizes, int n_in,
                              void* d_out, int out_size, void* d_ws, size_t ws_size,
                              hipStream_t stream)
{
    const float* x  = (const float*)d_in[0];
    const float* rp = (const float*)d_in[1];
    GrapherP g1 = {(const float*)d_in[2],  (const float*)d_in[3],
                   (const float*)d_in[4],  (const float*)d_in[5],
                   (const float*)d_in[6],  (const float*)d_in[7]};
    GrapherP g2 = {(const float*)d_in[8],  (const float*)d_in[9],
                   (const float*)d_in[10], (const float*)d_in[11],
                   (const float*)d_in[12], (const float*)d_in[13]};
    const float* f1w1 = (const float*)d_in[14]; const float* f1b1 = (const float*)d_in[15];
    const float* f1w2 = (const float*)d_in[16]; const float* f1b2 = (const float*)d_in[17];
    const float* f2w1 = (const float*)d_in[18]; const float* f2b1 = (const float*)d_in[19];
    const float* f2w2 = (const float*)d_in[20]; const float* f2b2 = (const float*)d_in[21];
    float* out = (float*)d_out;

    const size_t P  = (size_t)BB * CC * NN;     // 2,408,448 floats
    const size_t P4 = 4 * P;
    float* ws   = (float*)d_ws;
    float* bufA = ws;                 // P4 (conv out / ci / gather out: disjoint in time)
    float* bufB = bufA + P4;          // P4
    unsigned short* xnt = (unsigned short*)(bufB + P4);   // B*N*192 us == P floats
    float* cur0 = (float*)xnt + P;    // P
    float* cur1 = cur0 + P;           // P
    float* sqc  = cur1 + P;           // B*N
    int*   idx  = (int*)(sqc + (size_t)BB * NN);          // B*N*9 ints
    // xnf overlays the TAIL of bufA: gather writes only [0, 2P) of bufA,
    // ci occupies [0, ~0.9P) — the tail [3P, 4P) is free through the knn phase.
    float* xnf = bufA + 3 * P;        // B*N*96 floats = P

    run_grapher(x, rp, g1, cur0, bufA, bufB, xnt, xnf, sqc, idx, stream);
    run_ffn(cur0, f1w1, f1b1, f1w2, f1b2, cur1, bufA, bufB, stream);
    inorm(cur1, cur0, nullptr, CC, 2, stream);
    run_grapher(cur0, rp, g2, cur1, bufA, bufB, xnt, xnf, sqc, idx, stream);
    run_ffn(cur1, f2w1, f2b1, f2w2, f2b2, cur0, bufA, bufB, stream);
    inorm(cur0, out, x, CC, 0, stream);
}